// Round 1
// baseline (627.927 us; speedup 1.0000x reference)
//
#include <hip/hip_runtime.h>
#include <math.h>

#ifndef M_PI
#define M_PI 3.14159265358979323846
#endif

#define BB     128
#define TT     16384
#define PP     20
#define NCH    18
#define CHUNK  512
#define WARM   256
#define NCHUNK (TT / CHUNK)   // 32

// bipolar pair probe indices (LL, LP, RP, RL, Z groups, insertion order)
__constant__ int d_P1[NCH] = {0,4,5,6,  0,1,2,3,  11,15,16,17, 11,12,13,14, 8,9};
__constant__ int d_P2[NCH] = {4,5,6,7,  1,2,3,7,  15,16,17,18, 12,13,14,18, 9,10};

struct Coeffs {
    float b0h, b1h, b2h, a1h, a2h;   // highpass (normalized by a0)
    float b0l, b1l, b2l, a1l, a2l;   // lowpass
};

__global__ __launch_bounds__(256) void collate_iir(
    const float* __restrict__ x, const float* __restrict__ msk,
    float* __restrict__ out, Coeffs cf)
{
    int tid   = blockIdx.x * blockDim.x + threadIdx.x;
    int c     = tid % NCH;          // channel 0..17
    int g     = tid / NCH;          // row-chunk group
    int chunk = g & (NCHUNK - 1);   // 0..31
    int b     = g >> 5;             // 0..127   (g / NCHUNK)

    int p1 = d_P1[c];
    int p2 = d_P2[c];

    const float* xb = x   + (size_t)b * TT * PP;
    const float* mb = msk + (size_t)b * TT * PP;
    float* oe = out + ((size_t)b * NCH + c) * TT;                             // eegs
    float* om = out + (size_t)BB * NCH * TT + ((size_t)b * NCH + c) * TT;     // eeg_masks

    int tstart = chunk * CHUNK;
    int w0     = tstart - WARM;
    if (w0 < 0) w0 = 0;

    // direct-form-I state, zero initial conditions
    float hx1 = 0.f, hx2 = 0.f, hy1 = 0.f, hy2 = 0.f;   // highpass
    float lx1 = 0.f, lx2 = 0.f, ly1 = 0.f, ly2 = 0.f;   // lowpass
    float pm = 0.f, ly = 0.f;

#define STEP(t_)                                                              \
    {                                                                         \
        int idx = (t_) * PP;                                                  \
        float x1 = xb[idx + p1], x2 = xb[idx + p2];                           \
        float m1 = mb[idx + p1], m2 = mb[idx + p2];                           \
        pm = m1 * m2;                                                         \
        float v = (x1 - x2) * pm;                                             \
        float hy = cf.b0h * v + cf.b1h * hx1 + cf.b2h * hx2                   \
                 - cf.a1h * hy1 - cf.a2h * hy2;                               \
        hx2 = hx1; hx1 = v;  hy2 = hy1; hy1 = hy;                             \
        ly = cf.b0l * hy + cf.b1l * lx1 + cf.b2l * lx2                        \
           - cf.a1l * ly1 - cf.a2l * ly2;                                     \
        lx2 = lx1; lx1 = hy; ly2 = ly1; ly1 = ly;                             \
    }

    // warm-up region: run the filters, discard output
#pragma unroll 4
    for (int t = w0; t < tstart; ++t) {
        STEP(t);
    }

    // emit region
    int tend = tstart + CHUNK;
#pragma unroll 4
    for (int t = tstart; t < tend; ++t) {
        STEP(t);
        oe[t] = ly;
        om[t] = pm;
    }
#undef STEP
}

extern "C" void kernel_launch(void* const* d_in, const int* in_sizes, int n_in,
                              void* d_out, int out_size, void* d_ws, size_t ws_size,
                              hipStream_t stream)
{
    const float* x = (const float*)d_in[0];
    const float* m = (const float*)d_in[1];
    float* out = (float*)d_out;

    const double sr = 40.0, q = 0.7071067811865476;
    Coeffs cf;
    {   // highpass fc = 0.5
        double w0 = 2.0 * M_PI * 0.5 / sr;
        double al = sin(w0) / (2.0 * q);
        double cw = cos(w0);
        double a0 = 1.0 + al;
        cf.b0h = (float)(((1.0 + cw) * 0.5) / a0);
        cf.b1h = (float)((-(1.0 + cw)) / a0);
        cf.b2h = cf.b0h;
        cf.a1h = (float)((-2.0 * cw) / a0);
        cf.a2h = (float)((1.0 - al) / a0);
    }
    {   // lowpass fc = 50
        double w0 = 2.0 * M_PI * 50.0 / sr;
        double al = sin(w0) / (2.0 * q);
        double cw = cos(w0);
        double a0 = 1.0 + al;
        cf.b0l = (float)(((1.0 - cw) * 0.5) / a0);
        cf.b1l = (float)((1.0 - cw) / a0);
        cf.b2l = cf.b0l;
        cf.a1l = (float)((-2.0 * cw) / a0);
        cf.a2l = (float)((1.0 - al) / a0);
    }

    int total  = BB * NCHUNK * NCH;   // 73728
    int block  = 256;
    int grid   = total / block;       // 288
    collate_iir<<<grid, block, 0, stream>>>(x, m, out, cf);
}

// Round 2
// 425.634 us; speedup vs baseline: 1.4753x; 1.4753x over previous
//
#include <hip/hip_runtime.h>
#include <math.h>

#ifndef M_PI
#define M_PI 3.14159265358979323846
#endif

#define BB     128
#define TT     16384
#define PP     20
#define NCH    18
#define CHUNK  128
#define WARM   192
#define NCHUNK (TT / CHUNK)   // 128
#define BUF    16

// bipolar pair probe indices (LL, LP, RP, RL, Z groups, insertion order)
__constant__ int d_P1[NCH] = {0,4,5,6,  0,1,2,3,  11,15,16,17, 11,12,13,14, 8,9};
__constant__ int d_P2[NCH] = {4,5,6,7,  1,2,3,7,  15,16,17,18, 12,13,14,18, 9,10};

struct Coeffs {
    float b0h, b1h, b2h, a1h, a2h;   // highpass (normalized by a0)
    float b0l, b1l, b2l, a1l, a2l;   // lowpass
};

__global__ __launch_bounds__(256) void collate_iir(
    const float* __restrict__ x, const float* __restrict__ msk,
    float* __restrict__ out, Coeffs cf)
{
    int tid   = blockIdx.x * blockDim.x + threadIdx.x;
    int c     = tid % NCH;          // channel 0..17
    int g     = tid / NCH;          // row-chunk group
    int chunk = g & (NCHUNK - 1);   // 0..127
    int b     = g >> 7;             // 0..127   (g / NCHUNK)

    int p1 = d_P1[c];
    int p2 = d_P2[c];

    const float* xb = x   + (size_t)b * TT * PP;
    const float* mb = msk + (size_t)b * TT * PP;
    float* oe = out + ((size_t)b * NCH + c) * TT;                             // eegs
    float* om = out + (size_t)BB * NCH * TT + ((size_t)b * NCH + c) * TT;     // eeg_masks

    int tstart = chunk * CHUNK;
    int w0     = tstart - WARM;
    if (w0 < 0) w0 = 0;

    // direct-form-I state, zero initial conditions
    float hx1 = 0.f, hx2 = 0.f, hy1 = 0.f, hy2 = 0.f;   // highpass
    float lx1 = 0.f, lx2 = 0.f, ly1 = 0.f, ly2 = 0.f;   // lowpass
    float pm = 0.f, ly = 0.f;

#define STEP(t_)                                                              \
    {                                                                         \
        int idx = (t_) * PP;                                                  \
        float x1 = xb[idx + p1], x2 = xb[idx + p2];                           \
        float m1 = mb[idx + p1], m2 = mb[idx + p2];                           \
        pm = m1 * m2;                                                         \
        float v = (x1 - x2) * pm;                                             \
        float hy = cf.b0h * v + cf.b1h * hx1 + cf.b2h * hx2                   \
                 - cf.a1h * hy1 - cf.a2h * hy2;                               \
        hx2 = hx1; hx1 = v;  hy2 = hy1; hy1 = hy;                             \
        ly = cf.b0l * hy + cf.b1l * lx1 + cf.b2l * lx2                        \
           - cf.a1l * ly1 - cf.a2l * ly2;                                     \
        lx2 = lx1; lx1 = hy; ly2 = ly1; ly1 = ly;                             \
    }

    // warm-up region: run the filters, discard output
#pragma unroll 8
    for (int t = w0; t < tstart; ++t) {
        STEP(t);
    }

    // emit region: buffer BUF outputs in registers, store as float4
    for (int blk = 0; blk < CHUNK / BUF; ++blk) {
        float be[BUF], bm[BUF];
        int tbase = tstart + blk * BUF;
#pragma unroll
        for (int k = 0; k < BUF; ++k) {
            STEP(tbase + k);
            be[k] = ly;
            bm[k] = pm;
        }
        float4* oe4 = reinterpret_cast<float4*>(oe + tbase);
        float4* om4 = reinterpret_cast<float4*>(om + tbase);
#pragma unroll
        for (int q = 0; q < BUF / 4; ++q) {
            oe4[q] = make_float4(be[4*q+0], be[4*q+1], be[4*q+2], be[4*q+3]);
            om4[q] = make_float4(bm[4*q+0], bm[4*q+1], bm[4*q+2], bm[4*q+3]);
        }
    }
#undef STEP
}

extern "C" void kernel_launch(void* const* d_in, const int* in_sizes, int n_in,
                              void* d_out, int out_size, void* d_ws, size_t ws_size,
                              hipStream_t stream)
{
    const float* x = (const float*)d_in[0];
    const float* m = (const float*)d_in[1];
    float* out = (float*)d_out;

    const double sr = 40.0, q = 0.7071067811865476;
    Coeffs cf;
    {   // highpass fc = 0.5
        double w0 = 2.0 * M_PI * 0.5 / sr;
        double al = sin(w0) / (2.0 * q);
        double cw = cos(w0);
        double a0 = 1.0 + al;
        cf.b0h = (float)(((1.0 + cw) * 0.5) / a0);
        cf.b1h = (float)((-(1.0 + cw)) / a0);
        cf.b2h = cf.b0h;
        cf.a1h = (float)((-2.0 * cw) / a0);
        cf.a2h = (float)((1.0 - al) / a0);
    }
    {   // lowpass fc = 50
        double w0 = 2.0 * M_PI * 50.0 / sr;
        double al = sin(w0) / (2.0 * q);
        double cw = cos(w0);
        double a0 = 1.0 + al;
        cf.b0l = (float)(((1.0 - cw) * 0.5) / a0);
        cf.b1l = (float)((1.0 - cw) / a0);
        cf.b2l = cf.b0l;
        cf.a1l = (float)((-2.0 * cw) / a0);
        cf.a2l = (float)((1.0 - al) / a0);
    }

    int total  = BB * NCHUNK * NCH;   // 294912
    int block  = 256;
    int grid   = total / block;       // 1152
    collate_iir<<<grid, block, 0, stream>>>(x, m, out, cf);
}